// Round 1
// baseline (531.369 us; speedup 1.0000x reference)
//
#include <hip/hip_runtime.h>
#include <hip/hip_bf16.h>

#define T_SEQ   512
#define H_DIM   128
#define N3H     384
#define HSW     128   // h row stride (ushort): 256B rows + 16B-chunk XOR swizzle
#define XS      72    // x row stride (ushort): 144B -> rotation, conflict-free

typedef float f32x4 __attribute__((ext_vector_type(4)));
typedef float f32x4u __attribute__((ext_vector_type(4), aligned(4)));
typedef __bf16 bf16x8 __attribute__((ext_vector_type(8)));
typedef unsigned short us8 __attribute__((ext_vector_type(8)));
typedef unsigned int u32x2 __attribute__((ext_vector_type(2)));

static __device__ __forceinline__ unsigned short f2bf(float f) {
    unsigned int u = __builtin_bit_cast(unsigned int, f);
    u += 0x7FFFu + ((u >> 16) & 1u);
    return (unsigned short)(u >> 16);
}

// v_cvt_pk_bf16_f32: lo = bf16(a), hi = bf16(b), RNE.
static __device__ __forceinline__ unsigned cvt_pk_bf16(float a, float b) {
    unsigned r;
    asm("v_cvt_pk_bf16_f32 %0, %1, %2" : "=v"(r) : "v"(a), "v"(b));
    return r;
}

// LDS-only barrier: lgkmcnt(0), vmcnt untouched -> global prefetch loads
// stay in flight across it.
static __device__ __forceinline__ void lds_barrier() {
    asm volatile("" ::: "memory");
    __builtin_amdgcn_s_waitcnt(0xC07F);
    __builtin_amdgcn_s_barrier();
    asm volatile("" ::: "memory");
}

static __device__ __forceinline__ bf16x8 ld8(const unsigned short* p) {
    return __builtin_bit_cast(bf16x8, *(const us8*)p);
}

// 32 blocks x 16 batch rows x 256 threads (4 waves, 1/SIMD).
// Wave w owns col-groups {w, 4+w}: for each cg, tiles {cg, 8+cg, 16+cg} =
// z/r/hh for cols [16cg,16cg+16).  Two independent rec->gates chains per
// wave are software-pipelined: gates(cg0) overlaps rec-MFMA(cg1); the
// xw(t+1) MFMAs overlap gates(cg1).  Gate pre-activations are PRE-SCALED:
// z,r rows by -1/ln2 (sigmoid = 1/(1+exp2)), hh rows by +2/ln2
// (tanh(u) = 1 - 2/(1+exp2(u'))).
__global__ __launch_bounds__(256, 1) void gru_fused(
    const float* __restrict__ inputs, const float* __restrict__ Wx,
    const float* __restrict__ Wh, const float* __restrict__ bias,
    const float* __restrict__ W_state, const float* __restrict__ w1,
    const float* __restrict__ b1, const float* __restrict__ gamma,
    const float* __restrict__ beta, const float* __restrict__ mean,
    const float* __restrict__ var, const float* __restrict__ w2,
    const float* __restrict__ b2, float* __restrict__ out)
{
    __shared__ __attribute__((aligned(16))) unsigned short hb[2][16 * HSW];
    __shared__ __attribute__((aligned(16))) unsigned short xb[2][16 * XS];
    __shared__ float hf[16][H_DIM + 1];

    const int tid  = threadIdx.x;
    const int w    = tid >> 6;      // wave 0..3
    const int lane = tid & 63;
    const int m    = lane & 15;
    const int q    = lane >> 4;
    const int b0   = blockIdx.x * 16;

    const float SCL0 = -1.4426950408889634f;  // -1/ln2  (z,r)
    const float SCL2 =  2.8853900817779268f;  // +2/ln2  (hh)

    // ---- prescaled weight B-fragments in registers for all 512 steps ----
    bf16x8 whB[2][3][4];
    bf16x8 wxB[2][3][2];
    f32x4 binv[2][3], brecv[2][3];
#pragma unroll
    for (int c = 0; c < 2; ++c) {
        const int cg = w + 4 * c;
#pragma unroll
        for (int g = 0; g < 3; ++g) {
            const float s = (g < 2) ? SCL0 : SCL2;
            const int col = (8 * g + cg) * 16 + m;
#pragma unroll
            for (int k = 0; k < 4; ++k) {
                us8 tmp;
#pragma unroll
                for (int j = 0; j < 8; ++j) tmp[j] = f2bf(s * Wh[(32 * k + 8 * q + j) * N3H + col]);
                whB[c][g][k] = __builtin_bit_cast(bf16x8, tmp);
            }
#pragma unroll
            for (int k = 0; k < 2; ++k) {
                us8 tmp;
#pragma unroll
                for (int j = 0; j < 8; ++j) tmp[j] = f2bf(s * Wx[(32 * k + 8 * q + j) * N3H + col]);
                wxB[c][g][k] = __builtin_bit_cast(bf16x8, tmp);
            }
            const float bi = s * bias[col];
            const float br = s * bias[N3H + col];
            binv[c][g]  = (f32x4){ bi, bi, bi, bi };
            brecv[c][g] = (f32x4){ br, br, br, br };
        }
    }

    // loop-invariant LDS offsets (ushort units), XOR-swizzled h layout:
    // logical 16B-chunk c of row r lives at physical chunk c^(r&7)
    // (bit 3 of the chunk index is untouched: 8+x ^ y = 8+(x^y) for y<8).
    int hro[4], hwo[2][4], xro[2];
#pragma unroll
    for (int k = 0; k < 4; ++k) hro[k] = m * HSW + (((4 * k + q) ^ (m & 7)) * 8);
#pragma unroll
    for (int c = 0; c < 2; ++c) {
        const int cg = w + 4 * c;
#pragma unroll
        for (int i = 0; i < 4; ++i) {
            const int row = 4 * q + i;
            hwo[c][i] = row * HSW + (((2 * cg + (m >> 3)) ^ (row & 7)) * 8) + (m & 7);
        }
    }
#pragma unroll
    for (int k = 0; k < 2; ++k) xro[k] = m * XS + 32 * k + 8 * q;

    // staging: ALL 256 threads load one float4 (row sr, cols 4sc..4sc+3)
    const int sr = tid >> 4, sc = tid & 15;
    const int xwoff = sr * XS + sc * 4;
    const float* xsrc = inputs + ((size_t)(b0 + sr) * T_SEQ) * 65 + sc * 4;

    auto xpack = [&](f32x4u v) -> u32x2 {
        u32x2 r;
        r[0] = cvt_pk_bf16(v[0], v[1]);
        r[1] = cvt_pk_bf16(v[2], v[3]);
        return r;
    };

    // zero h(0)
    {
        unsigned int* p = (unsigned int*)hb[0];
        for (int i = tid; i < 16 * HSW / 2; i += 256) p[i] = 0;
    }
    // stage x(0), x(1)
    {
        f32x4u v0 = *(const f32x4u*)(xsrc + 0 * 65);
        f32x4u v1 = *(const f32x4u*)(xsrc + 1 * 65);
        *(u32x2*)&xb[0][xwoff] = xpack(v0);
        *(u32x2*)&xb[1][xwoff] = xpack(v1);
    }
    lds_barrier();

    // xw(0)
    f32x4 xwA[2][3], xwB[2][3];
    {
        bf16x8 xa[2];
#pragma unroll
        for (int k = 0; k < 2; ++k) xa[k] = ld8(&xb[0][xro[k]]);
#pragma unroll
        for (int c = 0; c < 2; ++c)
#pragma unroll
            for (int g = 0; g < 3; ++g) {
                f32x4 acc = binv[c][g];
                acc = __builtin_amdgcn_mfma_f32_16x16x32_bf16(xa[0], wxB[c][g][0], acc, 0, 0, 0);
                acc = __builtin_amdgcn_mfma_f32_16x16x32_bf16(xa[1], wxB[c][g][1], acc, 0, 0, 0);
                xwA[c][g] = acc;
            }
    }

    f32x4u pf0 = *(const f32x4u*)(xsrc + 2 * 65);   // x(2)
    f32x4u pf1 = {};

    f32x4 hreg[2] = { { 0.f, 0.f, 0.f, 0.f }, { 0.f, 0.f, 0.f, 0.f } };

    auto step = [&](int t, f32x4 (*xw_cur)[3], f32x4 (*xw_next)[3],
                    f32x4u& pfLoad, f32x4u& pfUse,
                    const unsigned short* hcur, unsigned short* hnxt,
                    const unsigned short* xnxt, unsigned short* xwr) {
        // global prefetch x(t+3) — spans the barrier (vmcnt not drained)
        if (t <= T_SEQ - 4) pfLoad = *(const f32x4u*)(xsrc + (t + 3) * 65);

        lds_barrier();

        // issue all LDS reads up front (h fragments + next-step x fragments)
        bf16x8 ha[4];
#pragma unroll
        for (int k = 0; k < 4; ++k) ha[k] = ld8(&hcur[hro[k]]);
        bf16x8 xa[2];
        if (t < T_SEQ - 1) {
#pragma unroll
            for (int k = 0; k < 2; ++k) xa[k] = ld8(&xnxt[xro[k]]);
        }

        // rec(t) = h(t) @ Wh' (prescaled) — both col-groups
        f32x4 racc[2][3];
#pragma unroll
        for (int c = 0; c < 2; ++c)
#pragma unroll
            for (int g = 0; g < 3; ++g) {
                f32x4 a1 = brecv[c][g];
                a1 = __builtin_amdgcn_mfma_f32_16x16x32_bf16(ha[0], whB[c][g][0], a1, 0, 0, 0);
                a1 = __builtin_amdgcn_mfma_f32_16x16x32_bf16(ha[1], whB[c][g][1], a1, 0, 0, 0);
                f32x4 a2 = { 0.f, 0.f, 0.f, 0.f };
                a2 = __builtin_amdgcn_mfma_f32_16x16x32_bf16(ha[2], whB[c][g][2], a2, 0, 0, 0);
                a2 = __builtin_amdgcn_mfma_f32_16x16x32_bf16(ha[3], whB[c][g][3], a2, 0, 0, 0);
                racc[c][g] = a1 + a2;
            }

        // gates for one col-group: a' already scaled.
        // z = 1/(1+exp2(az')), tanh = 1-2/(1+exp2(u'))
        auto do_gates = [&](int c) {
            f32x4 hnew;
#pragma unroll
            for (int i = 0; i < 4; ++i) {
                const float ea = __builtin_amdgcn_exp2f(xw_cur[c][0][i] + racc[c][0][i]);
                const float eb = __builtin_amdgcn_exp2f(xw_cur[c][1][i] + racc[c][1][i]);
                const float Pa = 1.0f + ea, Pb = 1.0f + eb;
                const float D  = __builtin_amdgcn_rcpf(Pa * Pb);
                const float z  = Pb * D;
                const float r  = Pa * D;
                const float u  = fmaf(r, racc[c][2][i], xw_cur[c][2][i]);
                const float ec = __builtin_amdgcn_exp2f(u);
                const float hh = fmaf(-2.0f, __builtin_amdgcn_rcpf(1.0f + ec), 1.0f);
                hnew[i] = fmaf(z, hreg[c][i] - hh, hh);
            }
            hreg[c] = hnew;
            const float h0 = hnew[0], h1 = hnew[1], h2 = hnew[2], h3 = hnew[3];
            const unsigned p01 = cvt_pk_bf16(h0, h1);
            const unsigned p23 = cvt_pk_bf16(h2, h3);
            hnxt[hwo[c][0]] = (unsigned short)(p01);
            hnxt[hwo[c][1]] = (unsigned short)(p01 >> 16);
            hnxt[hwo[c][2]] = (unsigned short)(p23);
            hnxt[hwo[c][3]] = (unsigned short)(p23 >> 16);
        };

        // gates cg0 runs under rec-MFMA(cg1) pipe time
        do_gates(0);

        // xw(t+1) — independent MFMA work issued before gates(cg1) so its
        // pipe time hides under the cg1 gate VALU phase
        if (t < T_SEQ - 1) {
#pragma unroll
            for (int c = 0; c < 2; ++c)
#pragma unroll
                for (int g = 0; g < 3; ++g) {
                    f32x4 acc = binv[c][g];
                    acc = __builtin_amdgcn_mfma_f32_16x16x32_bf16(xa[0], wxB[c][g][0], acc, 0, 0, 0);
                    acc = __builtin_amdgcn_mfma_f32_16x16x32_bf16(xa[1], wxB[c][g][1], acc, 0, 0, 0);
                    xw_next[c][g] = acc;
                }
        }

        do_gates(1);

        // stage x(t+2) into LDS at end of step (off the h critical path)
        if (t <= T_SEQ - 3) *(u32x2*)&xwr[xwoff] = xpack(pfUse);
    };

    for (int t = 0; t < T_SEQ; t += 2) {
        step(t,     xwA, xwB, pf1, pf0, hb[0], hb[1], xb[1], xb[0]);
        step(t + 1, xwB, xwA, pf0, pf1, hb[1], hb[0], xb[0], xb[1]);
    }

    // ---- fused tail: +W_state, w1/ReLU/BN, w2 ----
#pragma unroll
    for (int c = 0; c < 2; ++c)
#pragma unroll
        for (int i = 0; i < 4; ++i)
            hf[4 * q + i][(w + 4 * c) * 16 + m] = hreg[c][i];
    __syncthreads();

    {
        const int row = tid >> 4;
        const int c0  = (tid & 15) * 8;
        const float sf = inputs[((size_t)(b0 + row) * T_SEQ + (T_SEQ - 1)) * 65 + 64];
        int si = (int)sf;
        si = si < 0 ? 0 : (si > 2 ? 2 : si);
#pragma unroll
        for (int c = 0; c < 8; ++c)
            hf[row][c0 + c] += W_state[si * H_DIM + c0 + c];
    }
    __syncthreads();

    {
        const int row = tid >> 4;
        const int j0  = (tid & 15) * 4;
        f32x4 acc = { b1[j0], b1[j0 + 1], b1[j0 + 2], b1[j0 + 3] };
        for (int k = 0; k < H_DIM; ++k) {
            const float hv = hf[row][k];
            const f32x4u wv = *(const f32x4u*)(w1 + k * 64 + j0);
#pragma unroll
            for (int c = 0; c < 4; ++c) acc[c] = fmaf(hv, wv[c], acc[c]);
        }
        float v = 0.0f;
#pragma unroll
        for (int c = 0; c < 4; ++c) {
            const int j = j0 + c;
            float a = fmaxf(acc[c], 0.0f);
            a = (a - mean[j]) * rsqrtf(var[j] + 1e-3f) * gamma[j] + beta[j];
            v = fmaf(a, w2[j], v);
        }
        v += __shfl_down(v, 8);
        v += __shfl_down(v, 4);
        v += __shfl_down(v, 2);
        v += __shfl_down(v, 1);
        if ((tid & 15) == 0) out[b0 + row] = v + b2[0];
    }
}

extern "C" void kernel_launch(void* const* d_in, const int* in_sizes, int n_in,
                              void* d_out, int out_size, void* d_ws, size_t ws_size,
                              hipStream_t stream) {
    (void)in_sizes; (void)n_in; (void)out_size; (void)d_ws; (void)ws_size;
    const float* inputs  = (const float*)d_in[0];
    const float* Wx      = (const float*)d_in[1];
    const float* Wh      = (const float*)d_in[2];
    const float* bias    = (const float*)d_in[3];
    const float* W_state = (const float*)d_in[4];
    const float* w1      = (const float*)d_in[5];
    const float* b1      = (const float*)d_in[6];
    const float* gamma   = (const float*)d_in[7];
    const float* beta    = (const float*)d_in[8];
    const float* mean    = (const float*)d_in[9];
    const float* var     = (const float*)d_in[10];
    const float* w2      = (const float*)d_in[11];
    const float* b2      = (const float*)d_in[12];
    float* out = (float*)d_out;

    gru_fused<<<32, 256, 0, stream>>>(inputs, Wx, Wh, bias, W_state, w1, b1,
                                      gamma, beta, mean, var, w2, b2, out);
}

// Round 2
// 422.496 us; speedup vs baseline: 1.2577x; 1.2577x over previous
//
#include <hip/hip_runtime.h>
#include <hip/hip_bf16.h>

#define T_SEQ   512
#define H_DIM   128
#define N3H     384
#define HSW     128   // h row stride (ushort): 256B rows + 16B-chunk XOR swizzle
#define XS      72    // x row stride (ushort): 144B -> rotation, conflict-free

typedef float f32x4 __attribute__((ext_vector_type(4)));
typedef float f32x2 __attribute__((ext_vector_type(2)));
typedef __bf16 bf16x8 __attribute__((ext_vector_type(8)));
typedef unsigned short us8 __attribute__((ext_vector_type(8)));

static __device__ __forceinline__ unsigned short f2bf(float f) {
    unsigned int u = __builtin_bit_cast(unsigned int, f);
    u += 0x7FFFu + ((u >> 16) & 1u);
    return (unsigned short)(u >> 16);
}

// v_cvt_pk_bf16_f32: lo = bf16(a), hi = bf16(b), RNE (matches f2bf).
static __device__ __forceinline__ unsigned cvt_pk_bf16(float a, float b) {
    unsigned r;
    asm("v_cvt_pk_bf16_f32 %0, %1, %2" : "=v"(r) : "v"(a), "v"(b));
    return r;
}

// LDS-only barrier: lgkmcnt(0), vmcnt untouched -> global prefetch loads
// stay in flight across it.
static __device__ __forceinline__ void lds_barrier() {
    asm volatile("" ::: "memory");
    __builtin_amdgcn_s_waitcnt(0xC07F);
    __builtin_amdgcn_s_barrier();
    asm volatile("" ::: "memory");
}

static __device__ __forceinline__ bf16x8 ld8(const unsigned short* p) {
    return __builtin_bit_cast(bf16x8, *(const us8*)p);
}

// 32 blocks x 16 batch rows x 512 threads (8 waves, 2/SIMD).
// Wave w owns N-tiles {w, 8+w, 16+w}: z/r/hh for cols [16w,16w+16) wave-local.
// SIMD issue is ~saturated (R1 analysis) -> this revision is an instruction
// diet on the proven 8-wave structure:
//  - biases folded into MFMA acc inits (z,r: b_in+b_rec into xw chain; hh:
//    b_rec stays in rec chain since r multiplies it), no per-step v_movs
//  - rec = single 4-deep MFMA chain (no a1+a2 adds)
//  - gate math on f32x4 vectors -> v_pk_*_f32
//  - v_cvt_pk_bf16_f32 for h-writes and x staging
//  - staging spread across all 512 threads (2 floats each), symmetric waves
// Pre-activations are PRE-SCALED: z,r rows by -1/ln2 (sigmoid = 1/(1+exp2)),
// hh rows by +2/ln2 (tanh(u) = 1 - 2/(1+exp2(u'))).
__global__ __launch_bounds__(512, 1) void gru_fused(
    const float* __restrict__ inputs, const float* __restrict__ Wx,
    const float* __restrict__ Wh, const float* __restrict__ bias,
    const float* __restrict__ W_state, const float* __restrict__ w1,
    const float* __restrict__ b1, const float* __restrict__ gamma,
    const float* __restrict__ beta, const float* __restrict__ mean,
    const float* __restrict__ var, const float* __restrict__ w2,
    const float* __restrict__ b2, float* __restrict__ out)
{
    __shared__ __attribute__((aligned(16))) unsigned short hb[2][16 * HSW];
    __shared__ __attribute__((aligned(16))) unsigned short xb[2][16 * XS];
    __shared__ float hf[16][H_DIM + 1];

    const int tid  = threadIdx.x;
    const int w    = tid >> 6;      // wave 0..7
    const int lane = tid & 63;
    const int m    = lane & 15;
    const int q    = lane >> 4;
    const int b0   = blockIdx.x * 16;

    const float SCL0 = -1.4426950408889634f;  // -1/ln2  (z,r)
    const float SCL2 =  2.8853900817779268f;  // +2/ln2  (hh)

    // ---- prescaled weight B-fragments in registers for all 512 steps ----
    bf16x8 whB[3][4];
    bf16x8 wxB[3][2];
    f32x4 xinit[3];            // xw-chain C init (biases folded)
    f32x4 rinit2;              // rec-chain C init for hh gate (s2*b_rec)
    const f32x4 zero4 = { 0.f, 0.f, 0.f, 0.f };
#pragma unroll
    for (int g = 0; g < 3; ++g) {
        const float s = (g < 2) ? SCL0 : SCL2;
        const int col = (8 * g + w) * 16 + m;   // tile w / 8+w / 16+w
#pragma unroll
        for (int k = 0; k < 4; ++k) {
            us8 tmp;
#pragma unroll
            for (int j = 0; j < 8; ++j) tmp[j] = f2bf(s * Wh[(32 * k + 8 * q + j) * N3H + col]);
            whB[g][k] = __builtin_bit_cast(bf16x8, tmp);
        }
#pragma unroll
        for (int k = 0; k < 2; ++k) {
            us8 tmp;
#pragma unroll
            for (int j = 0; j < 8; ++j) tmp[j] = f2bf(s * Wx[(32 * k + 8 * q + j) * N3H + col]);
            wxB[g][k] = __builtin_bit_cast(bf16x8, tmp);
        }
        const float bi = s * bias[col];
        const float br = s * bias[N3H + col];
        if (g < 2) {
            const float bc = bi + br;     // z,r: both biases into xw chain
            xinit[g] = (f32x4){ bc, bc, bc, bc };
        } else {
            xinit[g] = (f32x4){ bi, bi, bi, bi };
            rinit2   = (f32x4){ br, br, br, br };  // r multiplies this part
        }
    }

    // loop-invariant LDS offsets (ushort units), XOR-swizzled h layout:
    // logical 16B-chunk c of row r lives at physical chunk c^(r&7).
    int hro[4], hwo[4], xro[2];
#pragma unroll
    for (int k = 0; k < 4; ++k) hro[k] = m * HSW + (((4 * k + q) ^ (m & 7)) * 8);
#pragma unroll
    for (int i = 0; i < 4; ++i) {
        const int row = 4 * q + i;
        hwo[i] = row * HSW + (((2 * w + (m >> 3)) ^ (row & 7)) * 8) + (m & 7);
    }
#pragma unroll
    for (int k = 0; k < 2; ++k) xro[k] = m * XS + 32 * k + 8 * q;

    // staging: ALL 512 threads, 2 consecutive floats each
    const int sr = tid >> 5;                 // batch row 0..15
    const int c2 = (tid & 31) * 2;           // col 0..62
    const int xwoff = sr * XS + c2;
    const float* xs = inputs + ((size_t)(b0 + sr) * T_SEQ) * 65 + c2;

    // zero h(0)
    {
        unsigned int* p = (unsigned int*)hb[0];
        for (int i = tid; i < 16 * HSW / 2; i += 512) p[i] = 0;
    }
    // stage x(0), x(1)
    *(unsigned*)&xb[0][xwoff] = cvt_pk_bf16(xs[0], xs[1]);
    *(unsigned*)&xb[1][xwoff] = cvt_pk_bf16(xs[65], xs[66]);
    lds_barrier();

    // xw(0)
    f32x4 xwA[3], xwB[3];
    {
        bf16x8 xa[2];
#pragma unroll
        for (int k = 0; k < 2; ++k) xa[k] = ld8(&xb[0][xro[k]]);
#pragma unroll
        for (int g = 0; g < 3; ++g) {
            f32x4 acc = __builtin_amdgcn_mfma_f32_16x16x32_bf16(xa[0], wxB[g][0], xinit[g], 0, 0, 0);
            acc = __builtin_amdgcn_mfma_f32_16x16x32_bf16(xa[1], wxB[g][1], acc, 0, 0, 0);
            xwA[g] = acc;
        }
    }

    float pf0a = xs[2 * 65], pf0b = xs[2 * 65 + 1];   // x(2)
    float pf1a = 0.f, pf1b = 0.f;

    f32x4 hreg = { 0.f, 0.f, 0.f, 0.f };

    auto step = [&](int t, f32x4* xw_cur, f32x4* xw_next,
                    float& pfLa, float& pfLb, float pfUa, float pfUb,
                    const unsigned short* hcur, unsigned short* hnxt,
                    const unsigned short* xnxt, unsigned short* xwr) {
        // global prefetch x(t+3) — spans the barrier (vmcnt not drained)
        if (t <= T_SEQ - 4) { pfLa = xs[(t + 3) * 65]; pfLb = xs[(t + 3) * 65 + 1]; }

        lds_barrier();

        // issue all LDS reads up front (h fragments + next-step x fragments)
        bf16x8 ha[4];
#pragma unroll
        for (int k = 0; k < 4; ++k) ha[k] = ld8(&hcur[hro[k]]);
        bf16x8 xa[2];
        if (t < T_SEQ - 1) {
#pragma unroll
            for (int k = 0; k < 2; ++k) xa[k] = ld8(&xnxt[xro[k]]);
        }

        // rec(t) = h(t) @ Wh' (prescaled) — single 4-deep chain per gate,
        // C initialized from persistent bias/zero vectors (no movs)
        f32x4 racc[3];
#pragma unroll
        for (int g = 0; g < 3; ++g) {
            f32x4 acc = __builtin_amdgcn_mfma_f32_16x16x32_bf16(ha[0], whB[g][0], (g == 2) ? rinit2 : zero4, 0, 0, 0);
            acc = __builtin_amdgcn_mfma_f32_16x16x32_bf16(ha[1], whB[g][1], acc, 0, 0, 0);
            acc = __builtin_amdgcn_mfma_f32_16x16x32_bf16(ha[2], whB[g][2], acc, 0, 0, 0);
            acc = __builtin_amdgcn_mfma_f32_16x16x32_bf16(ha[3], whB[g][3], acc, 0, 0, 0);
            racc[g] = acc;
        }

        // gates, vectorized (v_pk_*_f32); trans stays scalar (floor: 3 exp2
        // + 2 rcp per element).  a' already scaled: z = 1/(1+exp2(az')),
        // tanh = 1-2/(1+exp2(u')).
        f32x4 az = xw_cur[0] + racc[0];
        f32x4 ar = xw_cur[1] + racc[1];
        f32x4 ea, eb;
#pragma unroll
        for (int i = 0; i < 4; ++i) { ea[i] = __builtin_amdgcn_exp2f(az[i]); eb[i] = __builtin_amdgcn_exp2f(ar[i]); }
        f32x4 Pa = ea + 1.0f;
        f32x4 Pb = eb + 1.0f;
        f32x4 PP = Pa * Pb;
        f32x4 D;
#pragma unroll
        for (int i = 0; i < 4; ++i) D[i] = __builtin_amdgcn_rcpf(PP[i]);
        f32x4 z = Pb * D;        // 1/Pa
        f32x4 r = Pa * D;        // 1/Pb
        f32x4 u = r * racc[2] + xw_cur[2];
        f32x4 ec;
#pragma unroll
        for (int i = 0; i < 4; ++i) ec[i] = __builtin_amdgcn_exp2f(u[i]);
        f32x4 Pc = ec + 1.0f;
        f32x4 rc;
#pragma unroll
        for (int i = 0; i < 4; ++i) rc[i] = __builtin_amdgcn_rcpf(Pc[i]);
        f32x4 hh = -2.0f * rc + 1.0f;
        f32x4 hnew = z * (hreg - hh) + hh;
        hreg = hnew;

        // xw(t+1) — independent; overlaps the gate VALU phase on the MFMA pipe
        if (t < T_SEQ - 1) {
#pragma unroll
            for (int g = 0; g < 3; ++g) {
                f32x4 acc = __builtin_amdgcn_mfma_f32_16x16x32_bf16(xa[0], wxB[g][0], xinit[g], 0, 0, 0);
                acc = __builtin_amdgcn_mfma_f32_16x16x32_bf16(xa[1], wxB[g][1], acc, 0, 0, 0);
                xw_next[g] = acc;
            }
        }

        // write h(t+1) (swizzled scatter) via packed bf16 convert
        {
            const unsigned p01 = cvt_pk_bf16(hnew[0], hnew[1]);
            const unsigned p23 = cvt_pk_bf16(hnew[2], hnew[3]);
            hnxt[hwo[0]] = (unsigned short)(p01);
            hnxt[hwo[1]] = (unsigned short)(p01 >> 16);
            hnxt[hwo[2]] = (unsigned short)(p23);
            hnxt[hwo[3]] = (unsigned short)(p23 >> 16);
        }

        // stage x(t+2) into LDS at end of step (off the h critical path)
        if (t <= T_SEQ - 3) *(unsigned*)&xwr[xwoff] = cvt_pk_bf16(pfUa, pfUb);
    };

    for (int t = 0; t < T_SEQ; t += 2) {
        step(t,     xwA, xwB, pf1a, pf1b, pf0a, pf0b, hb[0], hb[1], xb[1], xb[0]);
        step(t + 1, xwB, xwA, pf0a, pf0b, pf1a, pf1b, hb[1], hb[0], xb[0], xb[1]);
    }

    // ---- fused tail: +W_state, w1/ReLU/BN, w2 ----
#pragma unroll
    for (int i = 0; i < 4; ++i)
        hf[4 * q + i][16 * w + m] = hreg[i];
    __syncthreads();

    {
        const int row = tid >> 5;
        const int c0  = (tid & 31) * 4;
        const float sf = inputs[((size_t)(b0 + row) * T_SEQ + (T_SEQ - 1)) * 65 + 64];
        int si = (int)sf;
        si = si < 0 ? 0 : (si > 2 ? 2 : si);
#pragma unroll
        for (int c = 0; c < 4; ++c)
            hf[row][c0 + c] += W_state[si * H_DIM + c0 + c];
    }
    __syncthreads();

    {
        const int row = tid >> 5;
        const int jj  = (tid & 31) * 2;
        f32x2 acc = { b1[jj], b1[jj + 1] };
        for (int k = 0; k < H_DIM; ++k) {
            const float hv = hf[row][k];
            const f32x2 wv = *(const f32x2*)(w1 + k * 64 + jj);
            acc[0] = fmaf(hv, wv[0], acc[0]);
            acc[1] = fmaf(hv, wv[1], acc[1]);
        }
        float v = 0.0f;
#pragma unroll
        for (int ii = 0; ii < 2; ++ii) {
            const int j = jj + ii;
            float a = fmaxf(acc[ii], 0.0f);
            a = (a - mean[j]) * rsqrtf(var[j] + 1e-3f) * gamma[j] + beta[j];
            v = fmaf(a, w2[j], v);
        }
        v += __shfl_down(v, 16);
        v += __shfl_down(v, 8);
        v += __shfl_down(v, 4);
        v += __shfl_down(v, 2);
        v += __shfl_down(v, 1);
        if ((tid & 31) == 0) out[b0 + row] = v + b2[0];
    }
}

extern "C" void kernel_launch(void* const* d_in, const int* in_sizes, int n_in,
                              void* d_out, int out_size, void* d_ws, size_t ws_size,
                              hipStream_t stream) {
    (void)in_sizes; (void)n_in; (void)out_size; (void)d_ws; (void)ws_size;
    const float* inputs  = (const float*)d_in[0];
    const float* Wx      = (const float*)d_in[1];
    const float* Wh      = (const float*)d_in[2];
    const float* bias    = (const float*)d_in[3];
    const float* W_state = (const float*)d_in[4];
    const float* w1      = (const float*)d_in[5];
    const float* b1      = (const float*)d_in[6];
    const float* gamma   = (const float*)d_in[7];
    const float* beta    = (const float*)d_in[8];
    const float* mean    = (const float*)d_in[9];
    const float* var     = (const float*)d_in[10];
    const float* w2      = (const float*)d_in[11];
    const float* b2      = (const float*)d_in[12];
    float* out = (float*)d_out;

    gru_fused<<<32, 512, 0, stream>>>(inputs, Wx, Wh, bias, W_state, w1, b1,
                                      gamma, beta, mean, var, w2, b2, out);
}

// Round 3
// 421.642 us; speedup vs baseline: 1.2602x; 1.0020x over previous
//
#include <hip/hip_runtime.h>
#include <hip/hip_bf16.h>

#define T_SEQ   512
#define H_DIM   128
#define N3H     384
#define HSW     128   // h row stride (ushort): 256B rows + 16B-chunk XOR swizzle
#define XS      72    // x row stride (ushort): 144B -> rotation, conflict-free

typedef float f32x4 __attribute__((ext_vector_type(4)));
typedef float f32x2 __attribute__((ext_vector_type(2)));
typedef float f32x4u __attribute__((ext_vector_type(4), aligned(4)));
typedef __bf16 bf16x8 __attribute__((ext_vector_type(8)));
typedef unsigned short us8 __attribute__((ext_vector_type(8)));
typedef unsigned int u32x2 __attribute__((ext_vector_type(2)));

static __device__ __forceinline__ unsigned short f2bf(float f) {
    unsigned int u = __builtin_bit_cast(unsigned int, f);
    u += 0x7FFFu + ((u >> 16) & 1u);
    return (unsigned short)(u >> 16);
}

// v_cvt_pk_bf16_f32: lo = bf16(a), hi = bf16(b), RNE (matches f2bf).
static __device__ __forceinline__ unsigned cvt_pk_bf16(float a, float b) {
    unsigned r;
    asm("v_cvt_pk_bf16_f32 %0, %1, %2" : "=v"(r) : "v"(a), "v"(b));
    return r;
}

// LDS-only barrier: lgkmcnt(0), vmcnt untouched -> global prefetch loads
// stay in flight across it.
static __device__ __forceinline__ void lds_barrier() {
    asm volatile("" ::: "memory");
    __builtin_amdgcn_s_waitcnt(0xC07F);
    __builtin_amdgcn_s_barrier();
    asm volatile("" ::: "memory");
}

static __device__ __forceinline__ bf16x8 ld8(const unsigned short* p) {
    return __builtin_bit_cast(bf16x8, *(const us8*)p);
}

// ===========================================================================
// Pre-pass: xw[b][t][:] = prescale * (x[b][t] @ Wx + biases), for ALL t, on
// all 256 CUs (the recurrence can only use 32).  Output stored f32 in the
// MFMA C-fragment layout the recurrent kernel consumes:
//   xw[ ((b_blk*512 + t)*24 + wave*3 + g) * 256 + lane*4 .. +3 ]
// so each wave reads its 3 gate tiles as three coalesced dwordx4 loads.
// z,r tiles carry s0*(b_in+b_rec); hh tile carries s2*b_in only (b_rec_h is
// multiplied by r, stays in the rec chain).
// ===========================================================================
__global__ __launch_bounds__(512, 1) void xw_prepass(
    const float* __restrict__ inputs, const float* __restrict__ Wx,
    const float* __restrict__ bias, float* __restrict__ xw)
{
    __shared__ __attribute__((aligned(16))) unsigned short xl[16][16 * XS];

    const int tid  = threadIdx.x;
    const int w    = tid >> 6;
    const int lane = tid & 63;
    const int m    = lane & 15;
    const int q    = lane >> 4;
    const int b_blk = blockIdx.x & 31;
    const int t0    = (blockIdx.x >> 5) * 16;
    const int b0    = b_blk * 16;

    const float SCL0 = -1.4426950408889634f;  // -1/ln2  (z,r)
    const float SCL2 =  2.8853900817779268f;  // +2/ln2  (hh)

    bf16x8 wxB[3][2];
    f32x4 xinit[3];
#pragma unroll
    for (int g = 0; g < 3; ++g) {
        const float s = (g < 2) ? SCL0 : SCL2;
        const int col = (8 * g + w) * 16 + m;
#pragma unroll
        for (int k = 0; k < 2; ++k) {
            us8 tmp;
#pragma unroll
            for (int j = 0; j < 8; ++j) tmp[j] = f2bf(s * Wx[(32 * k + 8 * q + j) * N3H + col]);
            wxB[g][k] = __builtin_bit_cast(bf16x8, tmp);
        }
        const float bi = s * bias[col];
        const float br = s * bias[N3H + col];
        const float bc = (g < 2) ? (bi + br) : bi;
        xinit[g] = (f32x4){ bc, bc, bc, bc };
    }

    int xro[2];
#pragma unroll
    for (int k = 0; k < 2; ++k) xro[k] = m * XS + 32 * k + 8 * q;

    // stage 16 timesteps of x for 16 batch rows into LDS (bf16)
    {
        const int tt   = tid & 15;
        const int r    = (tid >> 4) & 15;
        const int half = tid >> 8;   // 0/1 -> cols 0-31 / 32-63
        const float* src = inputs + ((size_t)(b0 + r) * T_SEQ + (t0 + tt)) * 65 + half * 32;
        unsigned short* dst = &xl[tt][r * XS + half * 32];
#pragma unroll
        for (int j = 0; j < 8; ++j) {
            f32x4u v = *(const f32x4u*)(src + 4 * j);
            u32x2 pk;
            pk[0] = cvt_pk_bf16(v[0], v[1]);
            pk[1] = cvt_pk_bf16(v[2], v[3]);
            *(u32x2*)(dst + 4 * j) = pk;
        }
    }
    __syncthreads();

    for (int tt = 0; tt < 16; ++tt) {
        bf16x8 xa[2];
#pragma unroll
        for (int k = 0; k < 2; ++k) xa[k] = ld8(&xl[tt][xro[k]]);
        float* outp = xw + ((size_t)(b_blk * 512 + t0 + tt) * 24 + w * 3) * 256 + lane * 4;
#pragma unroll
        for (int g = 0; g < 3; ++g) {
            f32x4 acc = __builtin_amdgcn_mfma_f32_16x16x32_bf16(xa[0], wxB[g][0], xinit[g], 0, 0, 0);
            acc = __builtin_amdgcn_mfma_f32_16x16x32_bf16(xa[1], wxB[g][1], acc, 0, 0, 0);
            *(f32x4*)(outp + g * 256) = acc;
        }
    }
}

// ===========================================================================
// Recurrent kernel: pure h-chain.  32 blocks x 16 batch rows x 512 threads
// (8 waves, 2/SIMD).  Wave w owns N-tiles {w, 8+w, 16+w}.  Per step:
// prefetch xw(t+1) (spans barrier) -> lds_barrier -> 4 ds_read h ->
// [setprio(1)] 12 rec MFMA [setprio(0)] -> gates (VALU+trans) -> 4 ds_write.
// ===========================================================================
__global__ __launch_bounds__(512, 1) void gru_rec(
    const float* __restrict__ inputs, const float* __restrict__ Wh,
    const float* __restrict__ bias, const float* __restrict__ xw,
    const float* __restrict__ W_state, const float* __restrict__ w1,
    const float* __restrict__ b1, const float* __restrict__ gamma,
    const float* __restrict__ beta, const float* __restrict__ mean,
    const float* __restrict__ var, const float* __restrict__ w2,
    const float* __restrict__ b2, float* __restrict__ out)
{
    __shared__ __attribute__((aligned(16))) unsigned short hb[2][16 * HSW];
    __shared__ float hf[16][H_DIM + 1];

    const int tid  = threadIdx.x;
    const int w    = tid >> 6;      // wave 0..7
    const int lane = tid & 63;
    const int m    = lane & 15;
    const int q    = lane >> 4;
    const int bI   = blockIdx.x;
    const int b0   = bI * 16;

    const float SCL0 = -1.4426950408889634f;
    const float SCL2 =  2.8853900817779268f;

    bf16x8 whB[3][4];
    f32x4 rinit2;
    const f32x4 zero4 = { 0.f, 0.f, 0.f, 0.f };
#pragma unroll
    for (int g = 0; g < 3; ++g) {
        const float s = (g < 2) ? SCL0 : SCL2;
        const int col = (8 * g + w) * 16 + m;
#pragma unroll
        for (int k = 0; k < 4; ++k) {
            us8 tmp;
#pragma unroll
            for (int j = 0; j < 8; ++j) tmp[j] = f2bf(s * Wh[(32 * k + 8 * q + j) * N3H + col]);
            whB[g][k] = __builtin_bit_cast(bf16x8, tmp);
        }
        if (g == 2) {
            const float br = s * bias[N3H + col];
            rinit2 = (f32x4){ br, br, br, br };
        }
    }

    int hro[4], hwo[4];
#pragma unroll
    for (int k = 0; k < 4; ++k) hro[k] = m * HSW + (((4 * k + q) ^ (m & 7)) * 8);
#pragma unroll
    for (int i = 0; i < 4; ++i) {
        const int row = 4 * q + i;
        hwo[i] = row * HSW + (((2 * w + (m >> 3)) ^ (row & 7)) * 8) + (m & 7);
    }

    // zero h(0)
    {
        unsigned int* p = (unsigned int*)hb[0];
        for (int i = tid; i < 16 * HSW / 2; i += 512) p[i] = 0;
    }

    // xw fragment pointer for this wave/lane; tiles g at +0/+256/+512 floats
    const float* xwp = xw + ((size_t)bI * 512 * 24 + w * 3) * 256 + lane * 4;
    f32x4 xwA[3], xwB[3];
#pragma unroll
    for (int g = 0; g < 3; ++g) xwA[g] = *(const f32x4u*)(xwp + g * 256);
    xwp += 24 * 256;   // -> t=1

    f32x4 hreg = { 0.f, 0.f, 0.f, 0.f };

    auto step = [&](int t, f32x4* cur, f32x4* nxt,
                    const unsigned short* hcur, unsigned short* hnxt) {
        // prefetch xw(t+1) — spans the barrier (vmcnt not drained)
        if (t < T_SEQ - 1) {
#pragma unroll
            for (int g = 0; g < 3; ++g) nxt[g] = *(const f32x4u*)(xwp + g * 256);
            xwp += 24 * 256;
        }

        lds_barrier();

        bf16x8 ha[4];
#pragma unroll
        for (int k = 0; k < 4; ++k) ha[k] = ld8(&hcur[hro[k]]);

        // rec(t) = h(t) @ Wh' — 4-deep chain per gate, C from persistent regs
        __builtin_amdgcn_s_setprio(1);
        f32x4 racc[3];
#pragma unroll
        for (int g = 0; g < 3; ++g) {
            f32x4 acc = __builtin_amdgcn_mfma_f32_16x16x32_bf16(ha[0], whB[g][0], (g == 2) ? rinit2 : zero4, 0, 0, 0);
            acc = __builtin_amdgcn_mfma_f32_16x16x32_bf16(ha[1], whB[g][1], acc, 0, 0, 0);
            acc = __builtin_amdgcn_mfma_f32_16x16x32_bf16(ha[2], whB[g][2], acc, 0, 0, 0);
            acc = __builtin_amdgcn_mfma_f32_16x16x32_bf16(ha[3], whB[g][3], acc, 0, 0, 0);
            racc[g] = acc;
        }
        __builtin_amdgcn_s_setprio(0);

        // gates: a' already scaled.  z = 1/(1+exp2(az')), tanh = 1-2/(1+exp2)
        f32x4 az = cur[0] + racc[0];
        f32x4 ar = cur[1] + racc[1];
        f32x4 ea, eb;
#pragma unroll
        for (int i = 0; i < 4; ++i) { ea[i] = __builtin_amdgcn_exp2f(az[i]); eb[i] = __builtin_amdgcn_exp2f(ar[i]); }
        f32x4 Pa = ea + 1.0f;
        f32x4 Pb = eb + 1.0f;
        f32x4 PP = Pa * Pb;
        f32x4 D;
#pragma unroll
        for (int i = 0; i < 4; ++i) D[i] = __builtin_amdgcn_rcpf(PP[i]);
        f32x4 z = Pb * D;        // 1/Pa
        f32x4 r = Pa * D;        // 1/Pb
        f32x4 u = r * racc[2] + cur[2];
        f32x4 ec;
#pragma unroll
        for (int i = 0; i < 4; ++i) ec[i] = __builtin_amdgcn_exp2f(u[i]);
        f32x4 Pc = ec + 1.0f;
        f32x4 rc;
#pragma unroll
        for (int i = 0; i < 4; ++i) rc[i] = __builtin_amdgcn_rcpf(Pc[i]);
        f32x4 hh = -2.0f * rc + 1.0f;
        f32x4 hnew = z * (hreg - hh) + hh;
        hreg = hnew;

        // write h(t+1) (swizzled scatter) via packed bf16 convert
        {
            const unsigned p01 = cvt_pk_bf16(hnew[0], hnew[1]);
            const unsigned p23 = cvt_pk_bf16(hnew[2], hnew[3]);
            hnxt[hwo[0]] = (unsigned short)(p01);
            hnxt[hwo[1]] = (unsigned short)(p01 >> 16);
            hnxt[hwo[2]] = (unsigned short)(p23);
            hnxt[hwo[3]] = (unsigned short)(p23 >> 16);
        }
    };

    for (int t = 0; t < T_SEQ; t += 2) {
        step(t,     xwA, xwB, hb[0], hb[1]);
        step(t + 1, xwB, xwA, hb[1], hb[0]);
    }

    // ---- fused tail: +W_state, w1/ReLU/BN, w2 ----
#pragma unroll
    for (int i = 0; i < 4; ++i)
        hf[4 * q + i][16 * w + m] = hreg[i];
    __syncthreads();

    {
        const int row = tid >> 5;
        const int c0  = (tid & 31) * 4;
        const float sf = inputs[((size_t)(b0 + row) * T_SEQ + (T_SEQ - 1)) * 65 + 64];
        int si = (int)sf;
        si = si < 0 ? 0 : (si > 2 ? 2 : si);
#pragma unroll
        for (int c = 0; c < 4; ++c)
            hf[row][c0 + c] += W_state[si * H_DIM + c0 + c];
    }
    __syncthreads();

    {
        const int row = tid >> 5;
        const int jj  = (tid & 31) * 2;
        f32x2 acc = { b1[jj], b1[jj + 1] };
        for (int k = 0; k < H_DIM; ++k) {
            const float hv = hf[row][k];
            const f32x2 wv = *(const f32x2*)(w1 + k * 64 + jj);
            acc[0] = fmaf(hv, wv[0], acc[0]);
            acc[1] = fmaf(hv, wv[1], acc[1]);
        }
        float v = 0.0f;
#pragma unroll
        for (int ii = 0; ii < 2; ++ii) {
            const int j = jj + ii;
            float a = fmaxf(acc[ii], 0.0f);
            a = (a - mean[j]) * rsqrtf(var[j] + 1e-3f) * gamma[j] + beta[j];
            v = fmaf(a, w2[j], v);
        }
        v += __shfl_down(v, 16);
        v += __shfl_down(v, 8);
        v += __shfl_down(v, 4);
        v += __shfl_down(v, 2);
        v += __shfl_down(v, 1);
        if ((tid & 31) == 0) out[b0 + row] = v + b2[0];
    }
}

// ===========================================================================
// Legacy fallback (R2 kernel, verified): used if workspace is too small.
// ===========================================================================
__global__ __launch_bounds__(512, 1) void gru_fused_legacy(
    const float* __restrict__ inputs, const float* __restrict__ Wx,
    const float* __restrict__ Wh, const float* __restrict__ bias,
    const float* __restrict__ W_state, const float* __restrict__ w1,
    const float* __restrict__ b1, const float* __restrict__ gamma,
    const float* __restrict__ beta, const float* __restrict__ mean,
    const float* __restrict__ var, const float* __restrict__ w2,
    const float* __restrict__ b2, float* __restrict__ out)
{
    __shared__ __attribute__((aligned(16))) unsigned short hb[2][16 * HSW];
    __shared__ __attribute__((aligned(16))) unsigned short xb[2][16 * XS];
    __shared__ float hf[16][H_DIM + 1];

    const int tid  = threadIdx.x;
    const int w    = tid >> 6;
    const int lane = tid & 63;
    const int m    = lane & 15;
    const int q    = lane >> 4;
    const int b0   = blockIdx.x * 16;

    const float SCL0 = -1.4426950408889634f;
    const float SCL2 =  2.8853900817779268f;

    bf16x8 whB[3][4];
    bf16x8 wxB[3][2];
    f32x4 xinit[3];
    f32x4 rinit2;
    const f32x4 zero4 = { 0.f, 0.f, 0.f, 0.f };
#pragma unroll
    for (int g = 0; g < 3; ++g) {
        const float s = (g < 2) ? SCL0 : SCL2;
        const int col = (8 * g + w) * 16 + m;
#pragma unroll
        for (int k = 0; k < 4; ++k) {
            us8 tmp;
#pragma unroll
            for (int j = 0; j < 8; ++j) tmp[j] = f2bf(s * Wh[(32 * k + 8 * q + j) * N3H + col]);
            whB[g][k] = __builtin_bit_cast(bf16x8, tmp);
        }
#pragma unroll
        for (int k = 0; k < 2; ++k) {
            us8 tmp;
#pragma unroll
            for (int j = 0; j < 8; ++j) tmp[j] = f2bf(s * Wx[(32 * k + 8 * q + j) * N3H + col]);
            wxB[g][k] = __builtin_bit_cast(bf16x8, tmp);
        }
        const float bi = s * bias[col];
        const float br = s * bias[N3H + col];
        if (g < 2) {
            const float bc = bi + br;
            xinit[g] = (f32x4){ bc, bc, bc, bc };
        } else {
            xinit[g] = (f32x4){ bi, bi, bi, bi };
            rinit2   = (f32x4){ br, br, br, br };
        }
    }

    int hro[4], hwo[4], xro[2];
#pragma unroll
    for (int k = 0; k < 4; ++k) hro[k] = m * HSW + (((4 * k + q) ^ (m & 7)) * 8);
#pragma unroll
    for (int i = 0; i < 4; ++i) {
        const int row = 4 * q + i;
        hwo[i] = row * HSW + (((2 * w + (m >> 3)) ^ (row & 7)) * 8) + (m & 7);
    }
#pragma unroll
    for (int k = 0; k < 2; ++k) xro[k] = m * XS + 32 * k + 8 * q;

    const int sr = tid >> 5;
    const int c2 = (tid & 31) * 2;
    const int xwoff = sr * XS + c2;
    const float* xs = inputs + ((size_t)(b0 + sr) * T_SEQ) * 65 + c2;

    {
        unsigned int* p = (unsigned int*)hb[0];
        for (int i = tid; i < 16 * HSW / 2; i += 512) p[i] = 0;
    }
    *(unsigned*)&xb[0][xwoff] = cvt_pk_bf16(xs[0], xs[1]);
    *(unsigned*)&xb[1][xwoff] = cvt_pk_bf16(xs[65], xs[66]);
    lds_barrier();

    f32x4 xwA[3], xwB[3];
    {
        bf16x8 xa[2];
#pragma unroll
        for (int k = 0; k < 2; ++k) xa[k] = ld8(&xb[0][xro[k]]);
#pragma unroll
        for (int g = 0; g < 3; ++g) {
            f32x4 acc = __builtin_amdgcn_mfma_f32_16x16x32_bf16(xa[0], wxB[g][0], xinit[g], 0, 0, 0);
            acc = __builtin_amdgcn_mfma_f32_16x16x32_bf16(xa[1], wxB[g][1], acc, 0, 0, 0);
            xwA[g] = acc;
        }
    }

    float pf0a = xs[2 * 65], pf0b = xs[2 * 65 + 1];
    float pf1a = 0.f, pf1b = 0.f;

    f32x4 hreg = { 0.f, 0.f, 0.f, 0.f };

    auto step = [&](int t, f32x4* xw_cur, f32x4* xw_next,
                    float& pfLa, float& pfLb, float pfUa, float pfUb,
                    const unsigned short* hcur, unsigned short* hnxt,
                    const unsigned short* xnxt, unsigned short* xwr) {
        if (t <= T_SEQ - 4) { pfLa = xs[(t + 3) * 65]; pfLb = xs[(t + 3) * 65 + 1]; }

        lds_barrier();

        bf16x8 ha[4];
#pragma unroll
        for (int k = 0; k < 4; ++k) ha[k] = ld8(&hcur[hro[k]]);
        bf16x8 xa[2];
        if (t < T_SEQ - 1) {
#pragma unroll
            for (int k = 0; k < 2; ++k) xa[k] = ld8(&xnxt[xro[k]]);
        }

        f32x4 racc[3];
#pragma unroll
        for (int g = 0; g < 3; ++g) {
            f32x4 acc = __builtin_amdgcn_mfma_f32_16x16x32_bf16(ha[0], whB[g][0], (g == 2) ? rinit2 : zero4, 0, 0, 0);
            acc = __builtin_amdgcn_mfma_f32_16x16x32_bf16(ha[1], whB[g][1], acc, 0, 0, 0);
            acc = __builtin_amdgcn_mfma_f32_16x16x32_bf16(ha[2], whB[g][2], acc, 0, 0, 0);
            acc = __builtin_amdgcn_mfma_f32_16x16x32_bf16(ha[3], whB[g][3], acc, 0, 0, 0);
            racc[g] = acc;
        }

        f32x4 az = xw_cur[0] + racc[0];
        f32x4 ar = xw_cur[1] + racc[1];
        f32x4 ea, eb;
#pragma unroll
        for (int i = 0; i < 4; ++i) { ea[i] = __builtin_amdgcn_exp2f(az[i]); eb[i] = __builtin_amdgcn_exp2f(ar[i]); }
        f32x4 Pa = ea + 1.0f;
        f32x4 Pb = eb + 1.0f;
        f32x4 PP = Pa * Pb;
        f32x4 D;
#pragma unroll
        for (int i = 0; i < 4; ++i) D[i] = __builtin_amdgcn_rcpf(PP[i]);
        f32x4 z = Pb * D;
        f32x4 r = Pa * D;
        f32x4 u = r * racc[2] + xw_cur[2];
        f32x4 ec;
#pragma unroll
        for (int i = 0; i < 4; ++i) ec[i] = __builtin_amdgcn_exp2f(u[i]);
        f32x4 Pc = ec + 1.0f;
        f32x4 rc;
#pragma unroll
        for (int i = 0; i < 4; ++i) rc[i] = __builtin_amdgcn_rcpf(Pc[i]);
        f32x4 hh = -2.0f * rc + 1.0f;
        f32x4 hnew = z * (hreg - hh) + hh;
        hreg = hnew;

        if (t < T_SEQ - 1) {
#pragma unroll
            for (int g = 0; g < 3; ++g) {
                f32x4 acc = __builtin_amdgcn_mfma_f32_16x16x32_bf16(xa[0], wxB[g][0], xinit[g], 0, 0, 0);
                acc = __builtin_amdgcn_mfma_f32_16x16x32_bf16(xa[1], wxB[g][1], acc, 0, 0, 0);
                xw_next[g] = acc;
            }
        }

        {
            const unsigned p01 = cvt_pk_bf16(hnew[0], hnew[1]);
            const unsigned p23 = cvt_pk_bf16(hnew[2], hnew[3]);
            hnxt[hwo[0]] = (unsigned short)(p01);
            hnxt[hwo[1]] = (unsigned short)(p01 >> 16);
            hnxt[hwo[2]] = (unsigned short)(p23);
            hnxt[hwo[3]] = (unsigned short)(p23 >> 16);
        }

        if (t <= T_SEQ - 3) *(unsigned*)&xwr[xwoff] = cvt_pk_bf16(pfUa, pfUb);
    };

    for (int t = 0; t < T_SEQ; t += 2) {
        step(t,     xwA, xwB, pf1a, pf1b, pf0a, pf0b, hb[0], hb[1], xb[1], xb[0]);
        step(t + 1, xwB, xwA, pf0a, pf0b, pf1a, pf1b, hb[1], hb[0], xb[0], xb[1]);
    }

#pragma unroll
    for (int i = 0; i < 4; ++i)
        hf[4 * q + i][16 * w + m] = hreg[i];
    __syncthreads();

    {
        const int row = tid >> 5;
        const int c0  = (tid & 31) * 4;
        const float sf = inputs[((size_t)(b0 + row) * T_SEQ + (T_SEQ - 1)) * 65 + 64];
        int si = (int)sf;
        si = si < 0 ? 0 : (si > 2 ? 2 : si);
#pragma unroll
        for (int c = 0; c < 4; ++c)
            hf[row][c0 + c] += W_state[si * H_DIM + c0 + c];
    }
    __syncthreads();

    {
        const int row = tid >> 5;
        const int jj  = (tid & 31) * 2;
        f32x2 acc = { b1[jj], b1[jj + 1] };
        for (int k = 0; k < H_DIM; ++k) {
            const float hv = hf[row][k];
            const f32x2 wv = *(const f32x2*)(w1 + k * 64 + jj);
            acc[0] = fmaf(hv, wv[0], acc[0]);
            acc[1] = fmaf(hv, wv[1], acc[1]);
        }
        float v = 0.0f;
#pragma unroll
        for (int ii = 0; ii < 2; ++ii) {
            const int j = jj + ii;
            float a = fmaxf(acc[ii], 0.0f);
            a = (a - mean[j]) * rsqrtf(var[j] + 1e-3f) * gamma[j] + beta[j];
            v = fmaf(a, w2[j], v);
        }
        v += __shfl_down(v, 16);
        v += __shfl_down(v, 8);
        v += __shfl_down(v, 4);
        v += __shfl_down(v, 2);
        v += __shfl_down(v, 1);
        if ((tid & 31) == 0) out[b0 + row] = v + b2[0];
    }
}

extern "C" void kernel_launch(void* const* d_in, const int* in_sizes, int n_in,
                              void* d_out, int out_size, void* d_ws, size_t ws_size,
                              hipStream_t stream) {
    (void)in_sizes; (void)n_in; (void)out_size;
    const float* inputs  = (const float*)d_in[0];
    const float* Wx      = (const float*)d_in[1];
    const float* Wh      = (const float*)d_in[2];
    const float* bias    = (const float*)d_in[3];
    const float* W_state = (const float*)d_in[4];
    const float* w1      = (const float*)d_in[5];
    const float* b1      = (const float*)d_in[6];
    const float* gamma   = (const float*)d_in[7];
    const float* beta    = (const float*)d_in[8];
    const float* mean    = (const float*)d_in[9];
    const float* var     = (const float*)d_in[10];
    const float* w2      = (const float*)d_in[11];
    const float* b2      = (const float*)d_in[12];
    float* out = (float*)d_out;

    const size_t XW_BYTES = (size_t)512 * T_SEQ * N3H * sizeof(float);  // 384 MiB
    if (d_ws != nullptr && ws_size >= XW_BYTES) {
        float* xw = (float*)d_ws;
        xw_prepass<<<1024, 512, 0, stream>>>(inputs, Wx, bias, xw);
        gru_rec<<<32, 512, 0, stream>>>(inputs, Wh, bias, xw, W_state, w1, b1,
                                        gamma, beta, mean, var, w2, b2, out);
    } else {
        gru_fused_legacy<<<32, 512, 0, stream>>>(inputs, Wx, Wh, bias, W_state,
                                                 w1, b1, gamma, beta, mean, var,
                                                 w2, b2, out);
    }
}

// Round 4
// 418.955 us; speedup vs baseline: 1.2683x; 1.0064x over previous
//
#include <hip/hip_runtime.h>
#include <hip/hip_bf16.h>

#define T_SEQ   512
#define H_DIM   128
#define N3H     384
#define HSW     128   // h row stride (ushort): 256B rows + 16B-chunk XOR swizzle
#define XS      72    // x row stride (ushort): 144B -> rotation, conflict-free

typedef float f32x4 __attribute__((ext_vector_type(4)));
typedef float f32x2 __attribute__((ext_vector_type(2)));
typedef __bf16 bf16x8 __attribute__((ext_vector_type(8)));
typedef unsigned short us8 __attribute__((ext_vector_type(8)));

static __device__ __forceinline__ unsigned short f2bf(float f) {
    unsigned int u = __builtin_bit_cast(unsigned int, f);
    u += 0x7FFFu + ((u >> 16) & 1u);
    return (unsigned short)(u >> 16);
}

// v_cvt_pk_bf16_f32: lo = bf16(a), hi = bf16(b), RNE (matches f2bf).
static __device__ __forceinline__ unsigned cvt_pk_bf16(float a, float b) {
    unsigned r;
    asm("v_cvt_pk_bf16_f32 %0, %1, %2" : "=v"(r) : "v"(a), "v"(b));
    return r;
}

// LDS-only barrier: lgkmcnt(0), vmcnt untouched -> global prefetch loads
// stay in flight across it.
static __device__ __forceinline__ void lds_barrier() {
    asm volatile("" ::: "memory");
    __builtin_amdgcn_s_waitcnt(0xC07F);
    __builtin_amdgcn_s_barrier();
    asm volatile("" ::: "memory");
}

static __device__ __forceinline__ bf16x8 ld8(const unsigned short* p) {
    return __builtin_bit_cast(bf16x8, *(const us8*)p);
}

// 32 blocks x 16 batch rows x 512 threads (8 waves, 2/SIMD).
// Wave w owns N-tiles {w, 8+w, 16+w}: z/r/hh for cols [16w,16w+16) wave-local.
//
// R4 theory: R2's step time (1542 cyc/SIMD) == MFMA-pipe busy (568) +
// VALU busy (777) + latency (~200) -- the two waves per SIMD are barrier
// phase-locked, so the MFMA and VALU pipes ping-pong instead of overlapping.
// This revision anti-phases the wave pair: EVEN waves raise s_setprio(1)
// around their MFMA cluster (rec + xw), odd waves stay prio 0.  After each
// barrier release even waves win MFMA-issue arbitration, odd waves' MFMA
// bursts slip behind, so odd gate-VALU overlaps even MFMA and vice versa.
// The independent xw(t+1) MFMAs are issued BEFORE the gate block so the
// transcendental burst overlaps their pipe drain.
__global__ __launch_bounds__(512, 1) void gru_fused(
    const float* __restrict__ inputs, const float* __restrict__ Wx,
    const float* __restrict__ Wh, const float* __restrict__ bias,
    const float* __restrict__ W_state, const float* __restrict__ w1,
    const float* __restrict__ b1, const float* __restrict__ gamma,
    const float* __restrict__ beta, const float* __restrict__ mean,
    const float* __restrict__ var, const float* __restrict__ w2,
    const float* __restrict__ b2, float* __restrict__ out)
{
    __shared__ __attribute__((aligned(16))) unsigned short hb[2][16 * HSW];
    __shared__ __attribute__((aligned(16))) unsigned short xb[2][16 * XS];
    __shared__ float hf[16][H_DIM + 1];
    extern __shared__ char ws_probe[];   // dynamic, unused: encodes ws_size
    (void)ws_probe;                      // bracket in LDS_Block_Size counter

    const int tid  = threadIdx.x;
    const int w    = tid >> 6;      // wave 0..7
    const int lane = tid & 63;
    const int m    = lane & 15;
    const int q    = lane >> 4;
    const int b0   = blockIdx.x * 16;
    const bool evenw = (w & 1) == 0;

    const float SCL0 = -1.4426950408889634f;  // -1/ln2  (z,r)
    const float SCL2 =  2.8853900817779268f;  // +2/ln2  (hh)

    // ---- prescaled weight B-fragments in registers for all 512 steps ----
    bf16x8 whB[3][4];
    bf16x8 wxB[3][2];
    f32x4 xinit[3];            // xw-chain C init (biases folded)
    f32x4 rinit2;              // rec-chain C init for hh gate (s2*b_rec)
    const f32x4 zero4 = { 0.f, 0.f, 0.f, 0.f };
#pragma unroll
    for (int g = 0; g < 3; ++g) {
        const float s = (g < 2) ? SCL0 : SCL2;
        const int col = (8 * g + w) * 16 + m;   // tile w / 8+w / 16+w
#pragma unroll
        for (int k = 0; k < 4; ++k) {
            us8 tmp;
#pragma unroll
            for (int j = 0; j < 8; ++j) tmp[j] = f2bf(s * Wh[(32 * k + 8 * q + j) * N3H + col]);
            whB[g][k] = __builtin_bit_cast(bf16x8, tmp);
        }
#pragma unroll
        for (int k = 0; k < 2; ++k) {
            us8 tmp;
#pragma unroll
            for (int j = 0; j < 8; ++j) tmp[j] = f2bf(s * Wx[(32 * k + 8 * q + j) * N3H + col]);
            wxB[g][k] = __builtin_bit_cast(bf16x8, tmp);
        }
        const float bi = s * bias[col];
        const float br = s * bias[N3H + col];
        if (g < 2) {
            const float bc = bi + br;     // z,r: both biases into xw chain
            xinit[g] = (f32x4){ bc, bc, bc, bc };
        } else {
            xinit[g] = (f32x4){ bi, bi, bi, bi };
            rinit2   = (f32x4){ br, br, br, br };  // r multiplies this part
        }
    }

    // loop-invariant LDS offsets (ushort units), XOR-swizzled h layout:
    // logical 16B-chunk c of row r lives at physical chunk c^(r&7).
    int hro[4], hwo[4], xro[2];
#pragma unroll
    for (int k = 0; k < 4; ++k) hro[k] = m * HSW + (((4 * k + q) ^ (m & 7)) * 8);
#pragma unroll
    for (int i = 0; i < 4; ++i) {
        const int row = 4 * q + i;
        hwo[i] = row * HSW + (((2 * w + (m >> 3)) ^ (row & 7)) * 8) + (m & 7);
    }
#pragma unroll
    for (int k = 0; k < 2; ++k) xro[k] = m * XS + 32 * k + 8 * q;

    // staging: ALL 512 threads, 2 consecutive floats each
    const int sr = tid >> 5;                 // batch row 0..15
    const int c2 = (tid & 31) * 2;           // col 0..62
    const int xwoff = sr * XS + c2;
    const float* xs = inputs + ((size_t)(b0 + sr) * T_SEQ) * 65 + c2;

    // zero h(0)
    {
        unsigned int* p = (unsigned int*)hb[0];
        for (int i = tid; i < 16 * HSW / 2; i += 512) p[i] = 0;
    }
    // stage x(0), x(1)
    *(unsigned*)&xb[0][xwoff] = cvt_pk_bf16(xs[0], xs[1]);
    *(unsigned*)&xb[1][xwoff] = cvt_pk_bf16(xs[65], xs[66]);
    lds_barrier();

    // xw(0)
    f32x4 xwA[3], xwB[3];
    {
        bf16x8 xa[2];
#pragma unroll
        for (int k = 0; k < 2; ++k) xa[k] = ld8(&xb[0][xro[k]]);
#pragma unroll
        for (int g = 0; g < 3; ++g) {
            f32x4 acc = __builtin_amdgcn_mfma_f32_16x16x32_bf16(xa[0], wxB[g][0], xinit[g], 0, 0, 0);
            acc = __builtin_amdgcn_mfma_f32_16x16x32_bf16(xa[1], wxB[g][1], acc, 0, 0, 0);
            xwA[g] = acc;
        }
    }

    float pf0a = xs[2 * 65], pf0b = xs[2 * 65 + 1];   // x(2)
    float pf1a = 0.f, pf1b = 0.f;

    f32x4 hreg = { 0.f, 0.f, 0.f, 0.f };

    auto step = [&](int t, f32x4* xw_cur, f32x4* xw_next,
                    float& pfLa, float& pfLb, float pfUa, float pfUb,
                    const unsigned short* hcur, unsigned short* hnxt,
                    const unsigned short* xnxt, unsigned short* xwr) {
        // global prefetch x(t+3) — spans the barrier (vmcnt not drained)
        if (t <= T_SEQ - 4) { pfLa = xs[(t + 3) * 65]; pfLb = xs[(t + 3) * 65 + 1]; }

        lds_barrier();

        // issue all LDS reads up front (h fragments + next-step x fragments)
        bf16x8 ha[4];
#pragma unroll
        for (int k = 0; k < 4; ++k) ha[k] = ld8(&hcur[hro[k]]);
        bf16x8 xa[2];
        if (t < T_SEQ - 1) {
#pragma unroll
            for (int k = 0; k < 2; ++k) xa[k] = ld8(&xnxt[xro[k]]);
        }

        // ---- MFMA cluster: rec chains + independent xw(t+1) ----
        // Even waves at prio 1 -> they win issue arbitration, odd waves'
        // MFMAs slip behind -> wave pair anti-phases, MFMA||VALU overlap.
        if (evenw) __builtin_amdgcn_s_setprio(1);

        f32x4 racc[3];
#pragma unroll
        for (int g = 0; g < 3; ++g) {
            f32x4 acc = __builtin_amdgcn_mfma_f32_16x16x32_bf16(ha[0], whB[g][0], (g == 2) ? rinit2 : zero4, 0, 0, 0);
            acc = __builtin_amdgcn_mfma_f32_16x16x32_bf16(ha[1], whB[g][1], acc, 0, 0, 0);
            acc = __builtin_amdgcn_mfma_f32_16x16x32_bf16(ha[2], whB[g][2], acc, 0, 0, 0);
            acc = __builtin_amdgcn_mfma_f32_16x16x32_bf16(ha[3], whB[g][3], acc, 0, 0, 0);
            racc[g] = acc;
        }

        // xw(t+1) — independent; issued before the gate block so the
        // transcendental burst below overlaps its pipe drain
        if (t < T_SEQ - 1) {
#pragma unroll
            for (int g = 0; g < 3; ++g) {
                f32x4 acc = __builtin_amdgcn_mfma_f32_16x16x32_bf16(xa[0], wxB[g][0], xinit[g], 0, 0, 0);
                acc = __builtin_amdgcn_mfma_f32_16x16x32_bf16(xa[1], wxB[g][1], acc, 0, 0, 0);
                xw_next[g] = acc;
            }
        }

        if (evenw) __builtin_amdgcn_s_setprio(0);

        // gates, vectorized; trans stays scalar (floor: 3 exp2 + 2 rcp per
        // element).  a' already scaled: z = 1/(1+exp2(az')),
        // tanh = 1-2/(1+exp2(u')).
        f32x4 az = xw_cur[0] + racc[0];
        f32x4 ar = xw_cur[1] + racc[1];
        f32x4 ea, eb;
#pragma unroll
        for (int i = 0; i < 4; ++i) { ea[i] = __builtin_amdgcn_exp2f(az[i]); eb[i] = __builtin_amdgcn_exp2f(ar[i]); }
        f32x4 Pa = ea + 1.0f;
        f32x4 Pb = eb + 1.0f;
        f32x4 PP = Pa * Pb;
        f32x4 D;
#pragma unroll
        for (int i = 0; i < 4; ++i) D[i] = __builtin_amdgcn_rcpf(PP[i]);
        f32x4 z = Pb * D;        // 1/Pa
        f32x4 r = Pa * D;        // 1/Pb
        f32x4 u = r * racc[2] + xw_cur[2];
        f32x4 ec;
#pragma unroll
        for (int i = 0; i < 4; ++i) ec[i] = __builtin_amdgcn_exp2f(u[i]);
        f32x4 Pc = ec + 1.0f;
        f32x4 rc;
#pragma unroll
        for (int i = 0; i < 4; ++i) rc[i] = __builtin_amdgcn_rcpf(Pc[i]);
        f32x4 hh = -2.0f * rc + 1.0f;
        f32x4 hnew = z * (hreg - hh) + hh;
        hreg = hnew;

        // write h(t+1) (swizzled scatter) via packed bf16 convert
        {
            const unsigned p01 = cvt_pk_bf16(hnew[0], hnew[1]);
            const unsigned p23 = cvt_pk_bf16(hnew[2], hnew[3]);
            hnxt[hwo[0]] = (unsigned short)(p01);
            hnxt[hwo[1]] = (unsigned short)(p01 >> 16);
            hnxt[hwo[2]] = (unsigned short)(p23);
            hnxt[hwo[3]] = (unsigned short)(p23 >> 16);
        }

        // stage x(t+2) into LDS at end of step (off the h critical path)
        if (t <= T_SEQ - 3) *(unsigned*)&xwr[xwoff] = cvt_pk_bf16(pfUa, pfUb);
    };

    for (int t = 0; t < T_SEQ; t += 2) {
        step(t,     xwA, xwB, pf1a, pf1b, pf0a, pf0b, hb[0], hb[1], xb[1], xb[0]);
        step(t + 1, xwB, xwA, pf0a, pf0b, pf1a, pf1b, hb[1], hb[0], xb[0], xb[1]);
    }

    // ---- fused tail: +W_state, w1/ReLU/BN, w2 ----
#pragma unroll
    for (int i = 0; i < 4; ++i)
        hf[4 * q + i][16 * w + m] = hreg[i];
    __syncthreads();

    {
        const int row = tid >> 5;
        const int c0  = (tid & 31) * 4;
        const float sf = inputs[((size_t)(b0 + row) * T_SEQ + (T_SEQ - 1)) * 65 + 64];
        int si = (int)sf;
        si = si < 0 ? 0 : (si > 2 ? 2 : si);
#pragma unroll
        for (int c = 0; c < 4; ++c)
            hf[row][c0 + c] += W_state[si * H_DIM + c0 + c];
    }
    __syncthreads();

    {
        const int row = tid >> 5;
        const int jj  = (tid & 31) * 2;
        f32x2 acc = { b1[jj], b1[jj + 1] };
        for (int k = 0; k < H_DIM; ++k) {
            const float hv = hf[row][k];
            const f32x2 wv = *(const f32x2*)(w1 + k * 64 + jj);
            acc[0] = fmaf(hv, wv[0], acc[0]);
            acc[1] = fmaf(hv, wv[1], acc[1]);
        }
        float v = 0.0f;
#pragma unroll
        for (int ii = 0; ii < 2; ++ii) {
            const int j = jj + ii;
            float a = fmaxf(acc[ii], 0.0f);
            a = (a - mean[j]) * rsqrtf(var[j] + 1e-3f) * gamma[j] + beta[j];
            v = fmaf(a, w2[j], v);
        }
        v += __shfl_down(v, 16);
        v += __shfl_down(v, 8);
        v += __shfl_down(v, 4);
        v += __shfl_down(v, 2);
        v += __shfl_down(v, 1);
        if ((tid & 31) == 0) out[b0 + row] = v + b2[0];
    }
}

extern "C" void kernel_launch(void* const* d_in, const int* in_sizes, int n_in,
                              void* d_out, int out_size, void* d_ws, size_t ws_size,
                              hipStream_t stream) {
    (void)in_sizes; (void)n_in; (void)out_size; (void)d_ws;
    const float* inputs  = (const float*)d_in[0];
    const float* Wx      = (const float*)d_in[1];
    const float* Wh      = (const float*)d_in[2];
    const float* bias    = (const float*)d_in[3];
    const float* W_state = (const float*)d_in[4];
    const float* w1      = (const float*)d_in[5];
    const float* b1      = (const float*)d_in[6];
    const float* gamma   = (const float*)d_in[7];
    const float* beta    = (const float*)d_in[8];
    const float* mean    = (const float*)d_in[9];
    const float* var     = (const float*)d_in[10];
    const float* w2      = (const float*)d_in[11];
    const float* b2      = (const float*)d_in[12];
    float* out = (float*)d_out;

    // ws_size probe (information only, zero behavior change): encode the
    // workspace bracket into dynamic-LDS size so LDS_Block_Size reveals it.
    //   <48Mi: 21504   >=48Mi: 21760   >=96Mi: 22272
    //   >=192Mi: 23296  >=256Mi: 25344
    const size_t Mi = 1024 * 1024;
    size_t probe = 0;
    if (ws_size >= 48 * Mi)  probe += 256;
    if (ws_size >= 96 * Mi)  probe += 512;
    if (ws_size >= 192 * Mi) probe += 1024;
    if (ws_size >= 256 * Mi) probe += 2048;

    gru_fused<<<32, 512, probe, stream>>>(inputs, Wx, Wh, bias, W_state, w1, b1,
                                          gamma, beta, mean, var, w2, b2, out);
}

// Round 6
// 408.467 us; speedup vs baseline: 1.3009x; 1.0257x over previous
//
#include <hip/hip_runtime.h>
#include <hip/hip_bf16.h>

#define T_SEQ   512
#define H_DIM   128
#define N3H     384
#define HSW     128   // h row stride (ushort): 256B rows + 16B-chunk XOR swizzle
#define XS      72    // x row stride (ushort): 144B -> rotation, conflict-free

typedef float f32x4 __attribute__((ext_vector_type(4)));
typedef float f32x2 __attribute__((ext_vector_type(2)));
typedef __bf16 bf16x8 __attribute__((ext_vector_type(8)));
typedef unsigned short us8 __attribute__((ext_vector_type(8)));

static __device__ __forceinline__ unsigned short f2bf(float f) {
    unsigned int u = __builtin_bit_cast(unsigned int, f);
    u += 0x7FFFu + ((u >> 16) & 1u);
    return (unsigned short)(u >> 16);
}

// v_cvt_pk_bf16_f32: lo = bf16(a), hi = bf16(b), RNE (matches f2bf).
// (verified passing in R2/R4 kernels)
static __device__ __forceinline__ unsigned cvt_pk_bf16(float a, float b) {
    unsigned r;
    asm("v_cvt_pk_bf16_f32 %0, %1, %2" : "=v"(r) : "v"(a), "v"(b));
    return r;
}

// LDS-only barrier: lgkmcnt(0), vmcnt untouched -> global prefetch loads
// stay in flight across it.
static __device__ __forceinline__ void lds_barrier() {
    asm volatile("" ::: "memory");
    __builtin_amdgcn_s_waitcnt(0xC07F);
    __builtin_amdgcn_s_barrier();
    asm volatile("" ::: "memory");
}

static __device__ __forceinline__ bf16x8 ld8(const unsigned short* p) {
    return __builtin_bit_cast(bf16x8, *(const us8*)p);
}

static __device__ __forceinline__ f32x2 lo2(f32x4 v) { return (f32x2){ v[0], v[1] }; }
static __device__ __forceinline__ f32x2 hi2(f32x4 v) { return (f32x2){ v[2], v[3] }; }

// 32 blocks x 16 batch rows x 512 threads (8 waves, 2/SIMD).
// Wave w owns N-tiles {w, 8+w, 16+w}: z/r/hh for cols [16w,16w+16) wave-local.
//
// R6 (disentangling R5's failure): keep the xw-into-MFMA-C fold (intrinsic
// path only, algebraically identical to R2), DROP the v_pk_* inline asm
// (suspected op_sel_hi default corrupted hi lanes).  Gate math on f32x2 with
// native vector ops + __builtin_elementwise_fma: compiler may select
// v_pk_{add,mul,fma}_f32 (v2f32 patterns exist on gfx90a+); scalar fallback
// is correct too.
// Pre-activations PRE-SCALED: z,r rows by -1/ln2 (sigmoid = 1/(1+exp2)),
// hh rows by +2/ln2 (tanh(u) = 1 - 2/(1+exp2(u'))).
__global__ __launch_bounds__(512, 1) void gru_fused(
    const float* __restrict__ inputs, const float* __restrict__ Wx,
    const float* __restrict__ Wh, const float* __restrict__ bias,
    const float* __restrict__ W_state, const float* __restrict__ w1,
    const float* __restrict__ b1, const float* __restrict__ gamma,
    const float* __restrict__ beta, const float* __restrict__ mean,
    const float* __restrict__ var, const float* __restrict__ w2,
    const float* __restrict__ b2, float* __restrict__ out)
{
    __shared__ __attribute__((aligned(16))) unsigned short hb[2][16 * HSW];
    __shared__ __attribute__((aligned(16))) unsigned short xb[2][16 * XS];
    __shared__ float hf[16][H_DIM + 1];

    const int tid  = threadIdx.x;
    const int w    = tid >> 6;      // wave 0..7
    const int lane = tid & 63;
    const int m    = lane & 15;
    const int q    = lane >> 4;
    const int b0   = blockIdx.x * 16;

    const float SCL0 = -1.4426950408889634f;  // -1/ln2  (z,r)
    const float SCL2 =  2.8853900817779268f;  // +2/ln2  (hh)

    // ---- prescaled weight B-fragments in registers for all 512 steps ----
    bf16x8 whB[3][4];
    bf16x8 wxB[3][2];
    f32x4 xinit[3];            // xw-chain C init (biases folded)
    f32x4 rinit2;              // rec-chain C init for hh gate (s2*b_rec)
#pragma unroll
    for (int g = 0; g < 3; ++g) {
        const float s = (g < 2) ? SCL0 : SCL2;
        const int col = (8 * g + w) * 16 + m;   // tile w / 8+w / 16+w
#pragma unroll
        for (int k = 0; k < 4; ++k) {
            us8 tmp;
#pragma unroll
            for (int j = 0; j < 8; ++j) tmp[j] = f2bf(s * Wh[(32 * k + 8 * q + j) * N3H + col]);
            whB[g][k] = __builtin_bit_cast(bf16x8, tmp);
        }
#pragma unroll
        for (int k = 0; k < 2; ++k) {
            us8 tmp;
#pragma unroll
            for (int j = 0; j < 8; ++j) tmp[j] = f2bf(s * Wx[(32 * k + 8 * q + j) * N3H + col]);
            wxB[g][k] = __builtin_bit_cast(bf16x8, tmp);
        }
        const float bi = s * bias[col];
        const float br = s * bias[N3H + col];
        if (g < 2) {
            const float bc = bi + br;     // z,r: both biases into xw chain
            xinit[g] = (f32x4){ bc, bc, bc, bc };
        } else {
            xinit[g] = (f32x4){ bi, bi, bi, bi };
            rinit2   = (f32x4){ br, br, br, br };  // r multiplies this part
        }
    }

    // loop-invariant LDS offsets (ushort units), XOR-swizzled h layout:
    // logical 16B-chunk c of row r lives at physical chunk c^(r&7).
    int hro[4], hwo[4], xro[2];
#pragma unroll
    for (int k = 0; k < 4; ++k) hro[k] = m * HSW + (((4 * k + q) ^ (m & 7)) * 8);
#pragma unroll
    for (int i = 0; i < 4; ++i) {
        const int row = 4 * q + i;
        hwo[i] = row * HSW + (((2 * w + (m >> 3)) ^ (row & 7)) * 8) + (m & 7);
    }
#pragma unroll
    for (int k = 0; k < 2; ++k) xro[k] = m * XS + 32 * k + 8 * q;

    // staging: ALL 512 threads, 2 consecutive floats each
    const int sr = tid >> 5;                 // batch row 0..15
    const int c2 = (tid & 31) * 2;           // col 0..62
    const int xwoff = sr * XS + c2;
    const float* xs = inputs + ((size_t)(b0 + sr) * T_SEQ) * 65 + c2;

    // zero h(0)
    {
        unsigned int* p = (unsigned int*)hb[0];
        for (int i = tid; i < 16 * HSW / 2; i += 512) p[i] = 0;
    }
    // stage x(0), x(1)
    *(unsigned*)&xb[0][xwoff] = cvt_pk_bf16(xs[0], xs[1]);
    *(unsigned*)&xb[1][xwoff] = cvt_pk_bf16(xs[65], xs[66]);
    lds_barrier();

    // xw(0)
    f32x4 xwA[3], xwB[3];
    {
        bf16x8 xa[2];
#pragma unroll
        for (int k = 0; k < 2; ++k) xa[k] = ld8(&xb[0][xro[k]]);
#pragma unroll
        for (int g = 0; g < 3; ++g) {
            f32x4 acc = __builtin_amdgcn_mfma_f32_16x16x32_bf16(xa[0], wxB[g][0], xinit[g], 0, 0, 0);
            acc = __builtin_amdgcn_mfma_f32_16x16x32_bf16(xa[1], wxB[g][1], acc, 0, 0, 0);
            xwA[g] = acc;
        }
    }

    float pf0a = xs[2 * 65], pf0b = xs[2 * 65 + 1];   // x(2)
    float pf1a = 0.f, pf1b = 0.f;

    f32x2 hreg_lo = { 0.f, 0.f }, hreg_hi = { 0.f, 0.f };

    // one packed gate pair (native vector ops; compiler picks lowering).
    // az',ar' complete pre-acts; rc2 = s2*(rec_h+br); xw2 = s2*(xh+bi);
    // hold = previous h pair.  Returns new h pair.
    auto gate_pair = [&](f32x2 az, f32x2 ar, f32x2 rc2, f32x2 xw2,
                         f32x2 hold) -> f32x2 {
        f32x2 ea, eb;
        ea[0] = __builtin_amdgcn_exp2f(az[0]); ea[1] = __builtin_amdgcn_exp2f(az[1]);
        eb[0] = __builtin_amdgcn_exp2f(ar[0]); eb[1] = __builtin_amdgcn_exp2f(ar[1]);
        const f32x2 Pa = ea + 1.0f;
        const f32x2 Pb = eb + 1.0f;
        const f32x2 PP = Pa * Pb;
        f32x2 D;
        D[0] = __builtin_amdgcn_rcpf(PP[0]); D[1] = __builtin_amdgcn_rcpf(PP[1]);
        const f32x2 z = Pb * D;      // 1/Pa
        const f32x2 r = Pa * D;      // 1/Pb
        const f32x2 u = __builtin_elementwise_fma(r, rc2, xw2);
        f32x2 ec;
        ec[0] = __builtin_amdgcn_exp2f(u[0]); ec[1] = __builtin_amdgcn_exp2f(u[1]);
        const f32x2 Pc = ec + 1.0f;
        f32x2 rv;
        rv[0] = __builtin_amdgcn_rcpf(Pc[0]); rv[1] = __builtin_amdgcn_rcpf(Pc[1]);
        const f32x2 hh = __builtin_elementwise_fma((f32x2){ -2.f, -2.f }, rv,
                                                   (f32x2){ 1.f, 1.f });
        const f32x2 df = hold - hh;
        return __builtin_elementwise_fma(z, df, hh);   // z*(hold-hh) + hh
    };

    auto step = [&](int t, f32x4* xw_cur, f32x4* xw_next,
                    float& pfLa, float& pfLb, float pfUa, float pfUb,
                    const unsigned short* hcur, unsigned short* hnxt,
                    const unsigned short* xnxt, unsigned short* xwr) {
        // global prefetch x(t+3) — spans the barrier (vmcnt not drained)
        if (t <= T_SEQ - 4) { pfLa = xs[(t + 3) * 65]; pfLb = xs[(t + 3) * 65 + 1]; }

        lds_barrier();

        // issue all LDS reads up front (h fragments + next-step x fragments)
        bf16x8 ha[4];
#pragma unroll
        for (int k = 0; k < 4; ++k) ha[k] = ld8(&hcur[hro[k]]);
        bf16x8 xa[2];
        if (t < T_SEQ - 1) {
#pragma unroll
            for (int k = 0; k < 2; ++k) xa[k] = ld8(&xnxt[xro[k]]);
        }

        // rec(t) = h(t) @ Wh' — 4-deep chain per gate.  z,r chains start
        // from xw_cur[g]: the xw+rec add happens in the matrix pipe.
        f32x4 racc[3];
#pragma unroll
        for (int g = 0; g < 3; ++g) {
            f32x4 acc = __builtin_amdgcn_mfma_f32_16x16x32_bf16(ha[0], whB[g][0], (g == 2) ? rinit2 : xw_cur[g], 0, 0, 0);
            acc = __builtin_amdgcn_mfma_f32_16x16x32_bf16(ha[1], whB[g][1], acc, 0, 0, 0);
            acc = __builtin_amdgcn_mfma_f32_16x16x32_bf16(ha[2], whB[g][2], acc, 0, 0, 0);
            acc = __builtin_amdgcn_mfma_f32_16x16x32_bf16(ha[3], whB[g][3], acc, 0, 0, 0);
            racc[g] = acc;
        }

        // xw(t+1) — independent; issued before the gate block so the
        // transcendental burst overlaps its pipe drain
        if (t < T_SEQ - 1) {
#pragma unroll
            for (int g = 0; g < 3; ++g) {
                f32x4 acc = __builtin_amdgcn_mfma_f32_16x16x32_bf16(xa[0], wxB[g][0], xinit[g], 0, 0, 0);
                acc = __builtin_amdgcn_mfma_f32_16x16x32_bf16(xa[1], wxB[g][1], acc, 0, 0, 0);
                xw_next[g] = acc;
            }
        }

        // gates on two element-pairs
        const f32x2 hn_lo = gate_pair(lo2(racc[0]), lo2(racc[1]),
                                      lo2(racc[2]), lo2(xw_cur[2]), hreg_lo);
        const f32x2 hn_hi = gate_pair(hi2(racc[0]), hi2(racc[1]),
                                      hi2(racc[2]), hi2(xw_cur[2]), hreg_hi);
        hreg_lo = hn_lo;
        hreg_hi = hn_hi;

        // write h(t+1) (swizzled scatter) via packed bf16 convert
        {
            const unsigned p01 = cvt_pk_bf16(hn_lo[0], hn_lo[1]);
            const unsigned p23 = cvt_pk_bf16(hn_hi[0], hn_hi[1]);
            hnxt[hwo[0]] = (unsigned short)(p01);
            hnxt[hwo[1]] = (unsigned short)(p01 >> 16);
            hnxt[hwo[2]] = (unsigned short)(p23);
            hnxt[hwo[3]] = (unsigned short)(p23 >> 16);
        }

        // stage x(t+2) into LDS at end of step (off the h critical path)
        if (t <= T_SEQ - 3) *(unsigned*)&xwr[xwoff] = cvt_pk_bf16(pfUa, pfUb);
    };

    for (int t = 0; t < T_SEQ; t += 2) {
        step(t,     xwA, xwB, pf1a, pf1b, pf0a, pf0b, hb[0], hb[1], xb[1], xb[0]);
        step(t + 1, xwB, xwA, pf0a, pf0b, pf1a, pf1b, hb[1], hb[0], xb[0], xb[1]);
    }

    // ---- fused tail: +W_state, w1/ReLU/BN, w2 ----
    hf[4 * q + 0][16 * w + m] = hreg_lo[0];
    hf[4 * q + 1][16 * w + m] = hreg_lo[1];
    hf[4 * q + 2][16 * w + m] = hreg_hi[0];
    hf[4 * q + 3][16 * w + m] = hreg_hi[1];
    __syncthreads();

    {
        const int row = tid >> 5;
        const int c0  = (tid & 31) * 4;
        const float sf = inputs[((size_t)(b0 + row) * T_SEQ + (T_SEQ - 1)) * 65 + 64];
        int si = (int)sf;
        si = si < 0 ? 0 : (si > 2 ? 2 : si);
#pragma unroll
        for (int c = 0; c < 4; ++c)
            hf[row][c0 + c] += W_state[si * H_DIM + c0 + c];
    }
    __syncthreads();

    {
        const int row = tid >> 5;
        const int jj  = (tid & 31) * 2;
        f32x2 acc = { b1[jj], b1[jj + 1] };
        for (int k = 0; k < H_DIM; ++k) {
            const float hv = hf[row][k];
            const f32x2 wv = *(const f32x2*)(w1 + k * 64 + jj);
            acc[0] = fmaf(hv, wv[0], acc[0]);
            acc[1] = fmaf(hv, wv[1], acc[1]);
        }
        float v = 0.0f;
#pragma unroll
        for (int ii = 0; ii < 2; ++ii) {
            const int j = jj + ii;
            float a = fmaxf(acc[ii], 0.0f);
            a = (a - mean[j]) * rsqrtf(var[j] + 1e-3f) * gamma[j] + beta[j];
            v = fmaf(a, w2[j], v);
        }
        v += __shfl_down(v, 16);
        v += __shfl_down(v, 8);
        v += __shfl_down(v, 4);
        v += __shfl_down(v, 2);
        v += __shfl_down(v, 1);
        if ((tid & 31) == 0) out[b0 + row] = v + b2[0];
    }
}

extern "C" void kernel_launch(void* const* d_in, const int* in_sizes, int n_in,
                              void* d_out, int out_size, void* d_ws, size_t ws_size,
                              hipStream_t stream) {
    (void)in_sizes; (void)n_in; (void)out_size; (void)d_ws; (void)ws_size;
    const float* inputs  = (const float*)d_in[0];
    const float* Wx      = (const float*)d_in[1];
    const float* Wh      = (const float*)d_in[2];
    const float* bias    = (const float*)d_in[3];
    const float* W_state = (const float*)d_in[4];
    const float* w1      = (const float*)d_in[5];
    const float* b1      = (const float*)d_in[6];
    const float* gamma   = (const float*)d_in[7];
    const float* beta    = (const float*)d_in[8];
    const float* mean    = (const float*)d_in[9];
    const float* var     = (const float*)d_in[10];
    const float* w2      = (const float*)d_in[11];
    const float* b2      = (const float*)d_in[12];
    float* out = (float*)d_out;

    gru_fused<<<32, 512, 0, stream>>>(inputs, Wx, Wh, bias, W_state, w1, b1,
                                      gamma, beta, mean, var, w2, b2, out);
}